// Round 6
// baseline (168.185 us; speedup 1.0000x reference)
//
#include <hip/hip_runtime.h>
#include <math.h>

#define BATCH 2
#define LSEQ  2048
#define DIMM  1024
#define NH    16
#define DH    64

typedef unsigned short ushortT;
typedef __attribute__((ext_vector_type(8))) short bf16x8;
typedef __attribute__((ext_vector_type(4))) float f32x4;

#define MFMA16(a, b, c) __builtin_amdgcn_mfma_f32_16x16x32_bf16((a), (b), (c), 0, 0, 0)

// scale folded into q columns of W_qkv: (1/sqrt(64)) * log2(e)
#define QSCALE 0.18033688011112042f

__device__ __forceinline__ ushortT f2bf(float f) {
    unsigned u = __float_as_uint(f);
    u += 0x7fffu + ((u >> 16) & 1u);   // RNE
    return (ushortT)(u >> 16);
}

// async global->LDS, 16B per lane. LDS dest is wave-uniform base + lane*16.
__device__ __forceinline__ void gll16(const ushortT* g, ushortT* l) {
    ushortT* gm = const_cast<ushortT*>(g);
    __builtin_amdgcn_global_load_lds(
        (__attribute__((address_space(1))) void*)gm,
        (__attribute__((address_space(3))) void*)l, 16, 0, 0);
}

// ---------------------------------------------------------------------------
// Fused prep: blocks [0,4096): x fp32->bf16; blocks [4096,8192): weight
// transposes W[K][N] fp32 -> Wt[N][K] bf16 (q-cols of W_qkv scaled by QSCALE).
// ---------------------------------------------------------------------------
__global__ __launch_bounds__(256) void prep(
    const float* __restrict__ x, ushortT* __restrict__ xb,
    const float* __restrict__ Wqkv, const float* __restrict__ Wout,
    ushortT* __restrict__ wqt, ushortT* __restrict__ wot)
{
    __shared__ float T[32][33];
    const int bx = blockIdx.x;
    const int tid = threadIdx.x;
    if (bx < 4096) {
        int i = bx * 256 + tid;
        float4 v = ((const float4*)x)[i];
        ushort4 o;
        o.x = f2bf(v.x); o.y = f2bf(v.y); o.z = f2bf(v.z); o.w = f2bf(v.w);
        ((ushort4*)xb)[i] = o;
        return;
    }
    const int id2 = bx - 4096;
    const int nb = id2 & 127, kb = id2 >> 7;
    const float* W; ushortT* Wt; int N, n0, nlimit;
    if (nb < 96) { W = Wqkv; Wt = wqt; N = 3 * DIMM; n0 = nb * 32; nlimit = DIMM; }
    else         { W = Wout; Wt = wot; N = DIMM;     n0 = (nb - 96) * 32; nlimit = 0; }
    const int k0 = kb * 32;
    const int c = tid & 31, r0 = tid >> 5;
#pragma unroll
    for (int p = 0; p < 4; ++p)
        T[r0 + 8 * p][c] = W[(size_t)(k0 + r0 + 8 * p) * N + n0 + c];
    __syncthreads();
#pragma unroll
    for (int p = 0; p < 4; ++p) {
        int rr = r0 + 8 * p;
        float v = T[c][rr];
        if (n0 + rr < nlimit) v *= QSCALE;
        Wt[(size_t)(n0 + rr) * DIMM + k0 + c] = f2bf(v);
    }
}

// ---------------------------------------------------------------------------
// R15: 128x128 tile, R14 single-barrier compiler-scheduled structure,
// 2 blocks/CU. R14 post-mortem: 256^2 @ 1 block/CU has no co-resident block
// to overlap the per-tile barrier drain (all 8 waves stall together), and
// only 192/256 CU coverage. 128^2: 256 thr (4 waves, 2Mx2N, wave=64x64 out),
// LDS 2 buf x (A[128][64]+B[128][64]) = 64 KiB -> 2 blocks/CU; grid 768 =
// full coverage + a resident pair per CU (m114 cross-block overlap: one
// block's MFMAs run while the other drains its barrier).
// Per K-tile: {issue all 8 staging DMAs FIRST | 16 ds_read_b128 + 32 MFMA
// compiler-interleaved (fine-grained lgkmcnt) | __syncthreads}.
// Swizzle: LDS[r][chunk c] = global[r][c ^ (r&7)] via pre-swizzled source
// (LDS linear, G21 both-sides rule); reader chunk (quad^sw), sw = li&7 = R&7.
// Per-element K accumulation order identical to R14 (s0 then s1, kt asc).
// ---------------------------------------------------------------------------
template<bool SWAP>
__device__ __forceinline__ void mainloop128(
    const ushortT* __restrict__ A, const ushortT* __restrict__ Bt,
    ushortT S[2][2][8192], int bm, int bn, int w, int lane, f32x4 acc[4][4])
{
    const int quad = lane >> 4, li = lane & 15;
    const int wm = w >> 1, wn = w & 1;
    const int sw = li & 7;
    const int s0 = (quad ^ sw) * 8, s1 = ((quad + 4) ^ sw) * 8;
    const int r8 = lane >> 3, c8 = lane & 7, cch = c8 ^ r8;
    // staging: wave w covers rows [32w, 32w+32) of each 128-row unit via
    // 4 gll16 at row offsets 8j; LDS dest linear (lane*16B == r8*128+c8*16).
    const ushortT* sA = A  + (size_t)(bm + 32 * w + r8) * DIMM + cch * 8;
    const ushortT* sB = Bt + (size_t)(bn + 32 * w + r8) * DIMM + cch * 8;
    const int ldb = (32 * w) * 64;              // wave-uniform LDS base (shorts)
    const int RSu = SWAP ? 1 : 0, CSu = SWAP ? 0 : 1;   // unit0=A, unit1=B

    {   // prologue: stage K-tile 0 into S[0], full drain (one-time)
#pragma unroll
        for (int j = 0; j < 4; ++j) {
            gll16(sA + (size_t)(8 * j) * DIMM, &S[0][0][ldb + 8 * j * 64]);
            gll16(sB + (size_t)(8 * j) * DIMM, &S[0][1][ldb + 8 * j * 64]);
        }
        __syncthreads();
    }

#pragma unroll 1
    for (int kt = 0; kt < 16; ++kt) {
        const int cur = kt & 1;
        if (kt < 15) {   // stage K-tile kt+1 into the other buffer, issue-first
            const int koff = (kt + 1) * 64;
#pragma unroll
            for (int j = 0; j < 4; ++j) {
                gll16(sA + (size_t)(8 * j) * DIMM + koff, &S[cur ^ 1][0][ldb + 8 * j * 64]);
                gll16(sB + (size_t)(8 * j) * DIMM + koff, &S[cur ^ 1][1][ldb + 8 * j * 64]);
            }
        }
        const ushortT* RS = &S[cur][RSu][0];
        const ushortT* CS = &S[cur][CSu][0];
        bf16x8 bfr[4][2];
#pragma unroll
        for (int ct = 0; ct < 4; ++ct) {
            const int R = wn * 64 + 16 * ct + li;
            bfr[ct][0] = *(const bf16x8*)&CS[R * 64 + s0];
            bfr[ct][1] = *(const bf16x8*)&CS[R * 64 + s1];
        }
        bf16x8 af[4][2];
#pragma unroll
        for (int rt = 0; rt < 4; ++rt) {
            const int R = wm * 64 + 16 * rt + li;
            af[rt][0] = *(const bf16x8*)&RS[R * 64 + s0];
            af[rt][1] = *(const bf16x8*)&RS[R * 64 + s1];
        }
#pragma unroll
        for (int rt = 0; rt < 4; ++rt) {
#pragma unroll
            for (int ct = 0; ct < 4; ++ct) {
                acc[rt][ct] = MFMA16(af[rt][0], bfr[ct][0], acc[rt][ct]);
                acc[rt][ct] = MFMA16(af[rt][1], bfr[ct][1], acc[rt][ct]);
            }
        }
        __syncthreads();   // drains staging DMAs (issued ~full tile ago) + LDS
    }
}

// ---------------------------------------------------------------------------
// GEMM1: qkv projection, 128^2 tiles, 256 threads, 768 blocks (2/CU).
// q/k via swapped mainloop -> vectorized [b,h,l,d] stores; v via normal
// mainloop -> vectorized transposed [b,h,d,l] stores.
// ---------------------------------------------------------------------------
__global__ __launch_bounds__(256, 2) void gemm_qkv(
    const ushortT* __restrict__ A, const ushortT* __restrict__ Bt,
    const float* __restrict__ bias,
    ushortT* __restrict__ qb, ushortT* __restrict__ kb, ushortT* __restrict__ vt)
{
    __shared__ __align__(16) ushortT S[2][2][8192];   // 64 KiB
    const int tid = threadIdx.x;
    const int w = tid >> 6, lane = tid & 63, quad = lane >> 4, li = lane & 15;
    const int wm = w >> 1, wn = w & 1;
    // bijective XCD swizzle (768 % 8 == 0): each XCD gets 96 consecutive
    // row-major tiles = 4 full M-rows -> A-panel (1 MB) L2-resident.
    const int bid = blockIdx.x;
    const int nbid = (bid & 7) * 96 + (bid >> 3);
    const int bx = nbid % 24, by = nbid / 24;
    const int bm = by * 128, bn = bx * 128;
    const int which = bx >> 3;                        // 0=q 1=k 2=v (uniform)
    const f32x4 z4 = {0.f, 0.f, 0.f, 0.f};
    f32x4 acc[4][4];
#pragma unroll
    for (int i = 0; i < 4; ++i)
#pragma unroll
        for (int j = 0; j < 4; ++j) acc[i][j] = z4;

    if (which == 2) {
        mainloop128<false>(A, Bt, S, bm, bn, w, lane, acc);
#pragma unroll
        for (int rt = 0; rt < 4; ++rt) {
            const int m = bm + wm * 64 + 16 * rt + quad * 4;
            const int b = m >> 11, l = m & 2047;
#pragma unroll
            for (int ct = 0; ct < 4; ++ct) {
                const int n = bn + wn * 64 + 16 * ct + li;
                const int nn = n & 1023;
                const int h = nn >> 6, dd = nn & 63;
                const float bterm = bias[n];
                ushort4 o4;
                o4.x = f2bf(acc[rt][ct][0] + bterm);
                o4.y = f2bf(acc[rt][ct][1] + bterm);
                o4.z = f2bf(acc[rt][ct][2] + bterm);
                o4.w = f2bf(acc[rt][ct][3] + bterm);
                *(ushort4*)(vt + ((size_t)(b * NH + h) * DH + dd) * LSEQ + l) = o4;
            }
        }
    } else {
        mainloop128<true>(A, Bt, S, bm, bn, w, lane, acc);
        const float bscale = (which == 0) ? QSCALE : 1.0f;
        ushortT* dst = (which == 0) ? qb : kb;
#pragma unroll
        for (int rt = 0; rt < 4; ++rt) {
            const int n0 = bn + wm * 64 + 16 * rt + quad * 4;   // 4 consecutive n
            const int nn0 = n0 & 1023;
            const int h = nn0 >> 6, dd = nn0 & 63;
            const float4 bv = *(const float4*)&bias[n0];
#pragma unroll
            for (int ct = 0; ct < 4; ++ct) {
                const int m = bm + wn * 64 + 16 * ct + li;
                const int b = m >> 11, l = m & 2047;
                ushort4 o4;
                o4.x = f2bf(acc[rt][ct][0] + bv.x * bscale);
                o4.y = f2bf(acc[rt][ct][1] + bv.y * bscale);
                o4.z = f2bf(acc[rt][ct][2] + bv.z * bscale);
                o4.w = f2bf(acc[rt][ct][3] + bv.w * bscale);
                *(ushort4*)(dst + ((size_t)(b * NH + h) * LSEQ + l) * DH + dd) = o4;
            }
        }
    }
}

// ---------------------------------------------------------------------------
// GEMM2: out = o @ W_out + b_out (fp32 out). 128(M)x64(N) tiles, BK=128.
// R13: bijective XCD swizzle (512 blocks = 8 XCDs x [4 bm-rows x 16 bn]):
// per-XCD working set = A-panel 1 MB + full B 2 MB < 4 MB L2.
// ---------------------------------------------------------------------------
__global__ __launch_bounds__(256) void gemm_out(
    const ushortT* __restrict__ A, const ushortT* __restrict__ Bt,
    const float* __restrict__ bias, float* __restrict__ out)
{
    __shared__ __align__(16) ushortT As[128 * 128];   // 32 KB
    __shared__ __align__(16) ushortT Bs[64 * 128];    // 16 KB
    const int tid = threadIdx.x;
    const int w = tid >> 6, lane = tid & 63, quad = lane >> 4, li = lane & 15;
    const int bid = blockIdx.x;
    const int xcd = bid & 7, sl = bid >> 3;           // xcd 0..7, sl 0..63
    const int bm = (xcd * 4 + (sl >> 4)) * 128;       // 4 bm-rows per XCD
    const int bn = (sl & 15) * 64;                    // all 16 bn per XCD
    const int wm = (w & 1) * 64, wn = (w >> 1) * 32;
    const int r4 = lane >> 4, c16 = lane & 15;
    const int sw = li & 7;

    const ushortT* pa[8]; ushortT* la[8];
#pragma unroll
    for (int j = 0; j < 8; ++j) {
        int Bi = w + 4 * j;
        int row = Bi * 4 + r4;
        int cxA = c16 ^ ((Bi & 1) * 4 + r4);       // == c16 ^ (row&7)
        pa[j] = A + (size_t)(bm + row) * DIMM + cxA * 8;
        la[j] = As + Bi * 512;
    }
    const ushortT* pb[4]; ushortT* lb[4];
#pragma unroll
    for (int j = 0; j < 4; ++j) {
        int Bi = w + 4 * j;
        int row = Bi * 4 + r4;
        int cxB = c16 ^ ((Bi & 1) * 4 + r4);
        pb[j] = Bt + (size_t)(bn + row) * DIMM + cxB * 8;
        lb[j] = Bs + Bi * 512;
    }

    const f32x4 z4 = {0.f, 0.f, 0.f, 0.f};
    f32x4 acc[4][2];
#pragma unroll
    for (int i = 0; i < 4; ++i) { acc[i][0] = z4; acc[i][1] = z4; }

    for (int k0 = 0; k0 < DIMM; k0 += 128) {
#pragma unroll
        for (int j = 0; j < 8; ++j) { gll16(pa[j], la[j]); pa[j] += 128; }
#pragma unroll
        for (int j = 0; j < 4; ++j) { gll16(pb[j], lb[j]); pb[j] += 128; }
        __syncthreads();
#pragma unroll
        for (int g = 0; g < 2; ++g) {
            const int s0 = (g * 8 + (quad ^ sw)) * 8;
            const int s1 = (g * 8 + ((quad + 4) ^ sw)) * 8;
            bf16x8 bfr[2][2];
#pragma unroll
            for (int t = 0; t < 2; ++t) {
                int R = wn + 16 * t + li;
                bfr[t][0] = *(const bf16x8*)&Bs[R * 128 + s0];
                bfr[t][1] = *(const bf16x8*)&Bs[R * 128 + s1];
            }
#pragma unroll
            for (int rt = 0; rt < 4; ++rt) {
                int R = wm + 16 * rt + li;
                bf16x8 a0 = *(const bf16x8*)&As[R * 128 + s0];
                bf16x8 a1 = *(const bf16x8*)&As[R * 128 + s1];
#pragma unroll
                for (int ct = 0; ct < 2; ++ct) {
                    acc[rt][ct] = MFMA16(a0, bfr[ct][0], acc[rt][ct]);
                    acc[rt][ct] = MFMA16(a1, bfr[ct][1], acc[rt][ct]);
                }
            }
        }
        __syncthreads();
    }
#pragma unroll
    for (int rt = 0; rt < 4; ++rt) {
#pragma unroll
        for (int ct = 0; ct < 2; ++ct) {
            int n = bn + wn + 16 * ct + li;
            float bterm = bias[n];
#pragma unroll
            for (int r = 0; r < 4; ++r) {
                int m = bm + wm + 16 * rt + quad * 4 + r;
                out[(size_t)m * DIMM + n] = acc[rt][ct][r] + bterm;
            }
        }
    }
}

// ---------------------------------------------------------------------------
// Flash attention, block-causal, transposed inner math, 128-KEY TILES.
// R9: softmax denominators via MFMA (A = ones, B = P^T fragments).
// R13: T5 setprio around MFMA clusters (kept; harmless).
// ---------------------------------------------------------------------------
__global__ __launch_bounds__(256, 2) void attn(
    const ushortT* __restrict__ qg, const ushortT* __restrict__ kg,
    const ushortT* __restrict__ vtg, ushortT* __restrict__ og)
{
    __shared__ __align__(16) ushortT Kbuf[2][8192];   // [p][half*4096 + blk*512]
    __shared__ __align__(16) ushortT Vbuf[2][8192];   // [d][l] halves
    __shared__ __align__(16) ushortT PsT[4096];       // 4 waves x 2 KB

    const int tid = threadIdx.x;
    const int w = tid >> 6, lane = tid & 63, quad = lane >> 4, li = lane & 15;
    const int id = blockIdx.x;                 // 0..511
    const int qt = (id < 256) ? (15 - (id >> 5)) : ((id - 256) >> 5);
    const int bhid = id & 31;
    const int b = bhid >> 4, h = bhid & 15;
    const size_t bh = (size_t)b * NH + h;
    const ushortT* qbase = qg + (bh * LSEQ + qt * 128) * DH;
    const ushortT* kbase = kg + bh * LSEQ * DH;
    const ushortT* vbase = vtg + bh * DH * LSEQ;
    ushortT* obase = og + ((size_t)b * LSEQ + qt * 128) * DIMM + h * DH;
    const f32x4 z4 = {0.f, 0.f, 0.f, 0.f};

    // ones A-fragment for the denominator MFMA (bf16 1.0 = 0x3F80)
    const short ONE = (short)0x3F80;
    const bf16x8 onesA = {ONE, ONE, ONE, ONE, ONE, ONE, ONE, ONE};

    // staging lane geometry (within each 8-row x 1KB DMA block)
    const int r8 = lane >> 3, c8 = lane & 7, cx = c8 ^ r8;

    bf16x8 qf[2][2];
#pragma unroll
    for (int band = 0; band < 2; ++band) {
        int row = 32 * w + 16 * band + li;
        qf[band][0] = *(const bf16x8*)(qbase + (size_t)row * DH + quad * 8);
        qf[band][1] = *(const bf16x8*)(qbase + (size_t)row * DH + 32 + quad * 8);
    }
    f32x4 oaccT[2][4];     // [band][dt]: O^T, lane owns qrow=li
    f32x4 lsacc[2];        // denominator acc (all 4 comps equal per lane)
#pragma unroll
    for (int i = 0; i < 2; ++i) {
        lsacc[i] = z4;
#pragma unroll
        for (int j = 0; j < 4; ++j) oaccT[i][j] = z4;
    }

    const int nt = qt + 1;                 // 128-key tiles
    // stage tile 0 (8 gll16/wave: 2 halves x {K,V} x 2 blocks)
#pragma unroll
    for (int s = 0; s < 2; ++s)
#pragma unroll
        for (int jj = 0; jj < 2; ++jj) {
            int B = w + 4 * jj;
            gll16(kbase + (size_t)(s * 64 + B * 8 + r8) * DH + cx * 8,
                  &Kbuf[0][s * 4096 + B * 512]);
            gll16(vbase + (size_t)(B * 8 + r8) * LSEQ + s * 64 + cx * 8,
                  &Vbuf[0][s * 4096 + B * 512]);
        }
    __syncthreads();

    const int sw = li & 7;
    const int pbase = w * 1024 + li * 8;

    for (int t = 0; t < nt; ++t) {
        const int p = t & 1;
        if (t + 1 < nt) {   // DMA next 128-key tile; drains at loop barrier
#pragma unroll
            for (int s = 0; s < 2; ++s)
#pragma unroll
                for (int jj = 0; jj < 2; ++jj) {
                    int B = w + 4 * jj;
                    gll16(kbase + (size_t)((t + 1) * 128 + s * 64 + B * 8 + r8) * DH + cx * 8,
                          &Kbuf[1 - p][s * 4096 + B * 512]);
                    gll16(vbase + (size_t)(B * 8 + r8) * LSEQ + (t + 1) * 128 + s * 64 + cx * 8,
                          &Vbuf[1 - p][s * 4096 + B * 512]);
                }
        }

#pragma unroll
        for (int s = 0; s < 2; ++s) {
            const ushortT* Kb = &Kbuf[p][s * 4096];
            const ushortT* Vb = &Vbuf[p][s * 4096];
            bf16x8 kf[4][2], vf[4][2];
#pragma unroll
            for (int ct = 0; ct < 4; ++ct) {
                int R = 16 * ct + li;
                kf[ct][0] = *(const bf16x8*)&Kb[R * 64 + (quad ^ sw) * 8];
                kf[ct][1] = *(const bf16x8*)&Kb[R * 64 + ((quad + 4) ^ sw) * 8];
            }
#pragma unroll
            for (int dt = 0; dt < 4; ++dt) {
                int R = 16 * dt + li;
                vf[dt][0] = *(const bf16x8*)&Vb[R * 64 + (quad ^ sw) * 8];
                vf[dt][1] = *(const bf16x8*)&Vb[R * 64 + ((quad + 4) ^ sw) * 8];
            }
#pragma unroll
            for (int band = 0; band < 2; ++band) {
                // S^T = K Q^T (pre-scaled, log2 domain)
                f32x4 sa[4];
                __builtin_amdgcn_s_setprio(1);
#pragma unroll
                for (int ct = 0; ct < 4; ++ct) {
                    sa[ct] = MFMA16(kf[ct][0], qf[band][0], z4);
                    sa[ct] = MFMA16(kf[ct][1], qf[band][1], sa[ct]);
                }
                __builtin_amdgcn_s_setprio(0);
                // exp2, pack 4 keys (RTZ bf16) via v_perm, one b64 write
#pragma unroll
                for (int ct = 0; ct < 4; ++ct) {
                    unsigned u0 = __float_as_uint(__builtin_amdgcn_exp2f(sa[ct][0]));
                    unsigned u1 = __float_as_uint(__builtin_amdgcn_exp2f(sa[ct][1]));
                    unsigned u2 = __float_as_uint(__builtin_amdgcn_exp2f(sa[ct][2]));
                    unsigned u3 = __float_as_uint(__builtin_amdgcn_exp2f(sa[ct][3]));
                    uint2 pk;
                    pk.x = __builtin_amdgcn_perm(u1, u0, 0x07060302u);
                    pk.y = __builtin_amdgcn_perm(u3, u2, 0x07060302u);
                    *(uint2*)&PsT[pbase + (2 * ct + (quad >> 1)) * 128 + (quad & 1) * 4] = pk;
                }
                // read P^T fragments once; use for BOTH denominator and PV
                bf16x8 pt0 = *(const bf16x8*)&PsT[pbase + quad * 128];
                bf16x8 pt1 = *(const bf16x8*)&PsT[pbase + (4 + quad) * 128];
                __builtin_amdgcn_s_setprio(1);
                lsacc[band] = MFMA16(onesA, pt0, lsacc[band]);   // denom += col-sums
                lsacc[band] = MFMA16(onesA, pt1, lsacc[band]);
#pragma unroll
                for (int dt = 0; dt < 4; ++dt) {
                    oaccT[band][dt] = MFMA16(vf[dt][0], pt0, oaccT[band][dt]);
                    oaccT[band][dt] = MFMA16(vf[dt][1], pt1, oaccT[band][dt]);
                }
                __builtin_amdgcn_s_setprio(0);
            }
        }
        __syncthreads();   // DMA drained + all readers of buf[p] done
    }

    // ---- normalize (denominator complete per-lane), store O (ushort4 on d) ----
#pragma unroll
    for (int band = 0; band < 2; ++band) {
        float inv = 1.0f / lsacc[band][0];
        int m = 32 * w + 16 * band + li;        // qrow
#pragma unroll
        for (int dt = 0; dt < 4; ++dt) {
            ushort4 o4;
            o4.x = f2bf(oaccT[band][dt][0] * inv);
            o4.y = f2bf(oaccT[band][dt][1] * inv);
            o4.z = f2bf(oaccT[band][dt][2] * inv);
            o4.w = f2bf(oaccT[band][dt][3] * inv);
            *(ushort4*)(obase + (size_t)m * DIMM + 16 * dt + quad * 4) = o4;
        }
    }
}

// ---------------------------------------------------------------------------
extern "C" void kernel_launch(void* const* d_in, const int* in_sizes, int n_in,
                              void* d_out, int out_size, void* d_ws, size_t ws_size,
                              hipStream_t stream)
{
    const float* x    = (const float*)d_in[0];
    const float* Wqkv = (const float*)d_in[1];
    const float* bqkv = (const float*)d_in[2];
    const float* Wout = (const float*)d_in[3];
    const float* bout = (const float*)d_in[4];

    const size_t M4 = (size_t)4 * 1024 * 1024;
    ushortT* ws  = (ushortT*)d_ws;
    ushortT* xb  = ws;                                  // 4M shorts
    ushortT* qb  = ws + M4;                             // 4M
    ushortT* kb  = ws + 2 * M4;                         // 4M
    ushortT* vt  = ws + 3 * M4;                         // 4M  [B,H,d,L]
    ushortT* ob  = ws + 4 * M4;                         // 4M  [B,L,H*d]
    ushortT* wqt = ws + 5 * M4;                         // 3M
    ushortT* wot = ws + 5 * M4 + (size_t)3 * 1024 * 1024;  // 1M

    prep<<<8192, 256, 0, stream>>>(x, xb, Wqkv, Wout, wqt, wot);
    gemm_qkv<<<dim3(768), 256, 0, stream>>>(xb, wqt, bqkv, qb, kb, vt);
    attn<<<dim3(512), 256, 0, stream>>>(qb, kb, vt, ob);
    gemm_out<<<dim3(512), 256, 0, stream>>>(ob, wot, bout, (float*)d_out);
}

// Round 7
// 159.557 us; speedup vs baseline: 1.0541x; 1.0541x over previous
//
#include <hip/hip_runtime.h>
#include <math.h>

#define BATCH 2
#define LSEQ  2048
#define DIMM  1024
#define NH    16
#define DH    64

typedef unsigned short ushortT;
typedef __attribute__((ext_vector_type(8))) short bf16x8;
typedef __attribute__((ext_vector_type(4))) float f32x4;

#define MFMA16(a, b, c) __builtin_amdgcn_mfma_f32_16x16x32_bf16((a), (b), (c), 0, 0, 0)

// scale folded into q columns of W_qkv: (1/sqrt(64)) * log2(e)
#define QSCALE 0.18033688011112042f

__device__ __forceinline__ ushortT f2bf(float f) {
    unsigned u = __float_as_uint(f);
    u += 0x7fffu + ((u >> 16) & 1u);   // RNE
    return (ushortT)(u >> 16);
}

// async global->LDS, 16B per lane. LDS dest is wave-uniform base + lane*16.
__device__ __forceinline__ void gll16(const ushortT* g, ushortT* l) {
    ushortT* gm = const_cast<ushortT*>(g);
    __builtin_amdgcn_global_load_lds(
        (__attribute__((address_space(1))) void*)gm,
        (__attribute__((address_space(3))) void*)l, 16, 0, 0);
}

// ---------------------------------------------------------------------------
// Fused prep: blocks [0,4096): x fp32->bf16; blocks [4096,8192): weight
// transposes W[K][N] fp32 -> Wt[N][K] bf16 (q-cols of W_qkv scaled by QSCALE).
// ---------------------------------------------------------------------------
__global__ __launch_bounds__(256) void prep(
    const float* __restrict__ x, ushortT* __restrict__ xb,
    const float* __restrict__ Wqkv, const float* __restrict__ Wout,
    ushortT* __restrict__ wqt, ushortT* __restrict__ wot)
{
    __shared__ float T[32][33];
    const int bx = blockIdx.x;
    const int tid = threadIdx.x;
    if (bx < 4096) {
        int i = bx * 256 + tid;
        float4 v = ((const float4*)x)[i];
        ushort4 o;
        o.x = f2bf(v.x); o.y = f2bf(v.y); o.z = f2bf(v.z); o.w = f2bf(v.w);
        ((ushort4*)xb)[i] = o;
        return;
    }
    const int id2 = bx - 4096;
    const int nb = id2 & 127, kb = id2 >> 7;
    const float* W; ushortT* Wt; int N, n0, nlimit;
    if (nb < 96) { W = Wqkv; Wt = wqt; N = 3 * DIMM; n0 = nb * 32; nlimit = DIMM; }
    else         { W = Wout; Wt = wot; N = DIMM;     n0 = (nb - 96) * 32; nlimit = 0; }
    const int k0 = kb * 32;
    const int c = tid & 31, r0 = tid >> 5;
#pragma unroll
    for (int p = 0; p < 4; ++p)
        T[r0 + 8 * p][c] = W[(size_t)(k0 + r0 + 8 * p) * N + n0 + c];
    __syncthreads();
#pragma unroll
    for (int p = 0; p < 4; ++p) {
        int rr = r0 + 8 * p;
        float v = T[c][rr];
        if (n0 + rr < nlimit) v *= QSCALE;
        Wt[(size_t)(n0 + rr) * DIMM + k0 + c] = f2bf(v);
    }
}

// ---------------------------------------------------------------------------
// R14 mainloop (kept): one barrier per K-tile, compiler-scheduled interior.
// R16 diagnosis: 6 mainloop variants all 44-48 µs @ MfmaUtil 19-21% — the
// invariant was the EPILOGUE (scattered 8B stores, ~3M write transactions
// ≈ 30 µs device-wide). Mainloop left as best-measured; epilogues rebuilt
// below as per-wave LDS transposes -> coalesced 128-512B stores.
// 256x256, 8 waves (2M x 4N), BK=64, 128 KiB LDS double-buffer, half-tiles
// ht0/1 = A rows 0-127/128-255, ht2/3 = B rows 0-127/128-255.
// ---------------------------------------------------------------------------
template<bool SWAP>
__device__ __forceinline__ void mainloop256(
    const ushortT* __restrict__ A, const ushortT* __restrict__ Bt,
    ushortT S[2][4][8192], int bm, int bn, int w, int lane, f32x4 acc[8][4])
{
    const int quad = lane >> 4, li = lane & 15;
    const int wm = w >> 2, wn = w & 3;
    const int sw = li & 7;
    const int s0 = (quad ^ sw) * 8, s1 = ((quad + 4) ^ sw) * 8;
    const int r8 = lane >> 3, c8 = lane & 7, cch = c8 ^ r8;
    const ushortT* sA = A  + (size_t)(bm + 16 * w + r8) * DIMM + cch * 8;
    const ushortT* sB = Bt + (size_t)(bn + 16 * w + r8) * DIMM + cch * 8;
    const int RSht = SWAP ? 2 + wm : wm;          // row-operand half-tile
    const int CSht = SWAP ? (wn >> 1) : 2 + (wn >> 1);  // col-operand half-tile
    const int cb64 = (wn & 1) * 64;               // row base within CS half-tile
    const int ld0 = (16 * w) * 64, ld1 = (16 * w + 8) * 64;

    {   // prologue: stage K-tile 0 into S[0], full drain (one-time)
#pragma unroll
        for (int P = 0; P < 4; ++P) {
            const ushortT* sp = ((P < 2) ? sA : sB) + (P & 1) * 128 * DIMM;
            gll16(sp,            &S[0][P][ld0]);
            gll16(sp + 8 * DIMM, &S[0][P][ld1]);
        }
        __syncthreads();
    }

#pragma unroll 1
    for (int kt = 0; kt < 16; ++kt) {
        const int cur = kt & 1;
        if (kt < 15) {   // stage K-tile kt+1 into the other buffer, issue-first
            const int koff = (kt + 1) * 64;
#pragma unroll
            for (int P = 0; P < 4; ++P) {
                const ushortT* sp = ((P < 2) ? sA : sB) + (P & 1) * 128 * DIMM + koff;
                gll16(sp,            &S[cur ^ 1][P][ld0]);
                gll16(sp + 8 * DIMM, &S[cur ^ 1][P][ld1]);
            }
        }
        const ushortT* RS = &S[cur][RSht][0];
        const ushortT* CS = &S[cur][CSht][0];
        bf16x8 bfr[4][2];
#pragma unroll
        for (int ct = 0; ct < 4; ++ct) {
            const int R = cb64 + 16 * ct + li;
            bfr[ct][0] = *(const bf16x8*)&CS[R * 64 + s0];
            bfr[ct][1] = *(const bf16x8*)&CS[R * 64 + s1];
        }
#pragma unroll
        for (int half = 0; half < 2; ++half) {
            bf16x8 af[4][2];
#pragma unroll
            for (int rt = 0; rt < 4; ++rt) {
                const int R = half * 64 + 16 * rt + li;
                af[rt][0] = *(const bf16x8*)&RS[R * 64 + s0];
                af[rt][1] = *(const bf16x8*)&RS[R * 64 + s1];
            }
#pragma unroll
            for (int rt = 0; rt < 4; ++rt) {
#pragma unroll
                for (int ct = 0; ct < 4; ++ct) {
                    acc[half * 4 + rt][ct] = MFMA16(af[rt][0], bfr[ct][0], acc[half * 4 + rt][ct]);
                    acc[half * 4 + rt][ct] = MFMA16(af[rt][1], bfr[ct][1], acc[half * 4 + rt][ct]);
                }
            }
        }
        __syncthreads();   // drains staging DMAs (issued ~full tile ago) + LDS
    }
}

// ---------------------------------------------------------------------------
// GEMM1: qkv projection, 256^2 tiles, 512 threads, 192 blocks (1/CU).
// R16: LDS-transpose epilogues. Old q/k stores were 8B @ 128B stride, v was
// 8B @ 4KB stride -> 64 line-transactions per store-inst, ~3M transactions
// total (~30 µs device-wide write-request bound). New: each wave stages its
// output block in its private 16KB slice of S (free after mainloop; no
// cross-wave barrier needed) with XOR chunk-swizzle c^((row&7)<<1), then
// reads back rows -> q/k: 512B fully-contiguous stores; v: 4x128B segments.
// ---------------------------------------------------------------------------
__global__ __launch_bounds__(512, 2) void gemm_qkv(
    const ushortT* __restrict__ A, const ushortT* __restrict__ Bt,
    const float* __restrict__ bias,
    ushortT* __restrict__ qb, ushortT* __restrict__ kb, ushortT* __restrict__ vt)
{
    __shared__ __align__(16) ushortT S[2][4][8192];   // 128 KiB
    const int tid = threadIdx.x;
    const int w = tid >> 6, lane = tid & 63, quad = lane >> 4, li = lane & 15;
    const int wm = w >> 2, wn = w & 3;
    // bijective XCD swizzle (192 % 8 == 0): each XCD gets 24 consecutive
    // tiles = 2 full M-panels -> A-panel L2 reuse.
    const int bid = blockIdx.x;
    const int nbid = (bid & 7) * 24 + (bid >> 3);
    const int bx = nbid % 12, by = nbid / 12;
    const int bm = by * 256, bn = bx * 256;
    const int which = bx >> 2;                        // 0=q 1=k 2=v (uniform)
    const f32x4 z4 = {0.f, 0.f, 0.f, 0.f};
    f32x4 acc[8][4];
#pragma unroll
    for (int i = 0; i < 8; ++i)
#pragma unroll
        for (int j = 0; j < 4; ++j) acc[i][j] = z4;

    ushortT* scr = &S[0][0][0] + w * 8192;   // 16 KB per-wave scratch
    const int mlr = lane >> 4, cc = lane & 15;
    const int b = bm >> 11;                  // block m-range stays in one batch

    if (which == 2) {
        mainloop256<false>(A, Bt, S, bm, bn, w, lane, acc);
        // stage wave block as scr[dd-local(64 rows)][l-local(128)] (bf16)
#pragma unroll
        for (int rt = 0; rt < 8; ++rt) {
            const int mc = (rt >> 2) * 16 + (rt & 3) * 4 + quad;   // l-chunk base
#pragma unroll
            for (int ct = 0; ct < 4; ++ct) {
                const int nl = 16 * ct + li;                       // dd-local row
                const float bterm = bias[bn + wn * 64 + nl];
                ushort4 o4;
                o4.x = f2bf(acc[rt][ct][0] + bterm);
                o4.y = f2bf(acc[rt][ct][1] + bterm);
                o4.z = f2bf(acc[rt][ct][2] + bterm);
                o4.w = f2bf(acc[rt][ct][3] + bterm);
                *(ushort4*)&scr[nl * 128 + (mc ^ ((nl & 7) << 1)) * 4] = o4;
            }
        }
        const int h = ((bn + wn * 64) & 1023) >> 6;                // wave-uniform
        ushortT* dbase = vt + (size_t)(b * NH + h) * DH * LSEQ;
#pragma unroll
        for (int rg = 0; rg < 16; ++rg) {
#pragma unroll
            for (int seg = 0; seg < 2; ++seg) {
                const int nl = rg * 4 + mlr;                       // dd-local
                const int c = seg * 16 + cc;
                ushort4 v4 = *(ushort4*)&scr[nl * 128 + (c ^ ((nl & 7) << 1)) * 4];
                const int l = (bm + wm * 128 + seg * 64 + cc * 4) & 2047;
                *(ushort4*)(dbase + (size_t)nl * LSEQ + l) = v4;   // 128B contig / 16 lanes
            }
        }
    } else {
        mainloop256<true>(A, Bt, S, bm, bn, w, lane, acc);
        const float bscale = (which == 0) ? QSCALE : 1.0f;
        ushortT* dst = (which == 0) ? qb : kb;
        // stage wave block as scr[l-local(64 rows)][d-local(128)] (bf16)
#pragma unroll
        for (int rt = 0; rt < 8; ++rt) {
            const int nlb = (rt >> 2) * 64 + (rt & 3) * 16 + quad * 4;  // d-local base
            const int nc = nlb >> 2;
            const float4 bv = *(const float4*)&bias[bn + wm * 128 + nlb];
#pragma unroll
            for (int ct = 0; ct < 4; ++ct) {
                const int ml = 16 * ct + li;                       // l-local row
                ushort4 o4;
                o4.x = f2bf(acc[rt][ct][0] + bv.x * bscale);
                o4.y = f2bf(acc[rt][ct][1] + bv.y * bscale);
                o4.z = f2bf(acc[rt][ct][2] + bv.z * bscale);
                o4.w = f2bf(acc[rt][ct][3] + bv.w * bscale);
                *(ushort4*)&scr[ml * 128 + (nc ^ ((ml & 7) << 1)) * 4] = o4;
            }
        }
#pragma unroll
        for (int rg = 0; rg < 16; ++rg) {
#pragma unroll
            for (int seg = 0; seg < 2; ++seg) {
                const int ml = rg * 4 + mlr;                       // l-local
                const int c = seg * 16 + cc;
                ushort4 v4 = *(ushort4*)&scr[ml * 128 + (c ^ ((ml & 7) << 1)) * 4];
                const int h = ((bn + wm * 128 + seg * 64) & 1023) >> 6;  // uniform/seg
                const int l = (bm + wn * 64 + ml) & 2047;
                *(ushort4*)(dst + ((size_t)(b * NH + h) * LSEQ + l) * DH + cc * 4) = v4;
            }   // 16 lanes x 8B contiguous (128B) x 4 l-rows contiguous = 512B/inst
        }
    }
}

// ---------------------------------------------------------------------------
// GEMM2: out = o @ W_out + b_out (fp32 out). 128(M)x64(N) tiles, BK=128.
// R13: bijective XCD swizzle (512 blocks = 8 XCDs x [4 bm-rows x 16 bn]):
// per-XCD working set = A-panel 1 MB + full B 2 MB < 4 MB L2.
// Stores already coalesced (lane -> consecutive n, fp32 rows).
// ---------------------------------------------------------------------------
__global__ __launch_bounds__(256) void gemm_out(
    const ushortT* __restrict__ A, const ushortT* __restrict__ Bt,
    const float* __restrict__ bias, float* __restrict__ out)
{
    __shared__ __align__(16) ushortT As[128 * 128];   // 32 KB
    __shared__ __align__(16) ushortT Bs[64 * 128];    // 16 KB
    const int tid = threadIdx.x;
    const int w = tid >> 6, lane = tid & 63, quad = lane >> 4, li = lane & 15;
    const int bid = blockIdx.x;
    const int xcd = bid & 7, sl = bid >> 3;           // xcd 0..7, sl 0..63
    const int bm = (xcd * 4 + (sl >> 4)) * 128;       // 4 bm-rows per XCD
    const int bn = (sl & 15) * 64;                    // all 16 bn per XCD
    const int wm = (w & 1) * 64, wn = (w >> 1) * 32;
    const int r4 = lane >> 4, c16 = lane & 15;
    const int sw = li & 7;

    const ushortT* pa[8]; ushortT* la[8];
#pragma unroll
    for (int j = 0; j < 8; ++j) {
        int Bi = w + 4 * j;
        int row = Bi * 4 + r4;
        int cxA = c16 ^ ((Bi & 1) * 4 + r4);       // == c16 ^ (row&7)
        pa[j] = A + (size_t)(bm + row) * DIMM + cxA * 8;
        la[j] = As + Bi * 512;
    }
    const ushortT* pb[4]; ushortT* lb[4];
#pragma unroll
    for (int j = 0; j < 4; ++j) {
        int Bi = w + 4 * j;
        int row = Bi * 4 + r4;
        int cxB = c16 ^ ((Bi & 1) * 4 + r4);
        pb[j] = Bt + (size_t)(bn + row) * DIMM + cxB * 8;
        lb[j] = Bs + Bi * 512;
    }

    const f32x4 z4 = {0.f, 0.f, 0.f, 0.f};
    f32x4 acc[4][2];
#pragma unroll
    for (int i = 0; i < 4; ++i) { acc[i][0] = z4; acc[i][1] = z4; }

    for (int k0 = 0; k0 < DIMM; k0 += 128) {
#pragma unroll
        for (int j = 0; j < 8; ++j) { gll16(pa[j], la[j]); pa[j] += 128; }
#pragma unroll
        for (int j = 0; j < 4; ++j) { gll16(pb[j], lb[j]); pb[j] += 128; }
        __syncthreads();
#pragma unroll
        for (int g = 0; g < 2; ++g) {
            const int s0 = (g * 8 + (quad ^ sw)) * 8;
            const int s1 = (g * 8 + ((quad + 4) ^ sw)) * 8;
            bf16x8 bfr[2][2];
#pragma unroll
            for (int t = 0; t < 2; ++t) {
                int R = wn + 16 * t + li;
                bfr[t][0] = *(const bf16x8*)&Bs[R * 128 + s0];
                bfr[t][1] = *(const bf16x8*)&Bs[R * 128 + s1];
            }
#pragma unroll
            for (int rt = 0; rt < 4; ++rt) {
                int R = wm + 16 * rt + li;
                bf16x8 a0 = *(const bf16x8*)&As[R * 128 + s0];
                bf16x8 a1 = *(const bf16x8*)&As[R * 128 + s1];
#pragma unroll
                for (int ct = 0; ct < 2; ++ct) {
                    acc[rt][ct] = MFMA16(a0, bfr[ct][0], acc[rt][ct]);
                    acc[rt][ct] = MFMA16(a1, bfr[ct][1], acc[rt][ct]);
                }
            }
        }
        __syncthreads();
    }
#pragma unroll
    for (int rt = 0; rt < 4; ++rt) {
#pragma unroll
        for (int ct = 0; ct < 2; ++ct) {
            int n = bn + wn + 16 * ct + li;
            float bterm = bias[n];
#pragma unroll
            for (int r = 0; r < 4; ++r) {
                int m = bm + wm + 16 * rt + quad * 4 + r;
                out[(size_t)m * DIMM + n] = acc[rt][ct][r] + bterm;
            }
        }
    }
}

// ---------------------------------------------------------------------------
// Flash attention, block-causal, transposed inner math, 128-KEY TILES.
// R9: softmax denominators via MFMA (A = ones, B = P^T fragments).
// R16: LDS-transpose O-epilogue. Old store was 8B @ 2KB stride (1M write
// transactions ~10 µs device-wide); new: stage per-wave 32x64 block in Kbuf
// (free after loop, per-wave region, no barrier), read rows -> 4x128B
// coalesced segments per inst (16x fewer transactions).
// ---------------------------------------------------------------------------
__global__ __launch_bounds__(256, 2) void attn(
    const ushortT* __restrict__ qg, const ushortT* __restrict__ kg,
    const ushortT* __restrict__ vtg, ushortT* __restrict__ og)
{
    __shared__ __align__(16) ushortT Kbuf[2][8192];   // [p][half*4096 + blk*512]
    __shared__ __align__(16) ushortT Vbuf[2][8192];   // [d][l] halves
    __shared__ __align__(16) ushortT PsT[4096];       // 4 waves x 2 KB

    const int tid = threadIdx.x;
    const int w = tid >> 6, lane = tid & 63, quad = lane >> 4, li = lane & 15;
    const int id = blockIdx.x;                 // 0..511
    const int qt = (id < 256) ? (15 - (id >> 5)) : ((id - 256) >> 5);
    const int bhid = id & 31;
    const int b = bhid >> 4, h = bhid & 15;
    const size_t bh = (size_t)b * NH + h;
    const ushortT* qbase = qg + (bh * LSEQ + qt * 128) * DH;
    const ushortT* kbase = kg + bh * LSEQ * DH;
    const ushortT* vbase = vtg + bh * DH * LSEQ;
    ushortT* obase = og + ((size_t)b * LSEQ + qt * 128) * DIMM + h * DH;
    const f32x4 z4 = {0.f, 0.f, 0.f, 0.f};

    // ones A-fragment for the denominator MFMA (bf16 1.0 = 0x3F80)
    const short ONE = (short)0x3F80;
    const bf16x8 onesA = {ONE, ONE, ONE, ONE, ONE, ONE, ONE, ONE};

    // staging lane geometry (within each 8-row x 1KB DMA block)
    const int r8 = lane >> 3, c8 = lane & 7, cx = c8 ^ r8;

    bf16x8 qf[2][2];
#pragma unroll
    for (int band = 0; band < 2; ++band) {
        int row = 32 * w + 16 * band + li;
        qf[band][0] = *(const bf16x8*)(qbase + (size_t)row * DH + quad * 8);
        qf[band][1] = *(const bf16x8*)(qbase + (size_t)row * DH + 32 + quad * 8);
    }
    f32x4 oaccT[2][4];     // [band][dt]: O^T, lane owns qrow=li
    f32x4 lsacc[2];        // denominator acc (all 4 comps equal per lane)
#pragma unroll
    for (int i = 0; i < 2; ++i) {
        lsacc[i] = z4;
#pragma unroll
        for (int j = 0; j < 4; ++j) oaccT[i][j] = z4;
    }

    const int nt = qt + 1;                 // 128-key tiles
    // stage tile 0 (8 gll16/wave: 2 halves x {K,V} x 2 blocks)
#pragma unroll
    for (int s = 0; s < 2; ++s)
#pragma unroll
        for (int jj = 0; jj < 2; ++jj) {
            int B = w + 4 * jj;
            gll16(kbase + (size_t)(s * 64 + B * 8 + r8) * DH + cx * 8,
                  &Kbuf[0][s * 4096 + B * 512]);
            gll16(vbase + (size_t)(B * 8 + r8) * LSEQ + s * 64 + cx * 8,
                  &Vbuf[0][s * 4096 + B * 512]);
        }
    __syncthreads();

    const int sw = li & 7;
    const int pbase = w * 1024 + li * 8;

    for (int t = 0; t < nt; ++t) {
        const int p = t & 1;
        if (t + 1 < nt) {   // DMA next 128-key tile; drains at loop barrier
#pragma unroll
            for (int s = 0; s < 2; ++s)
#pragma unroll
                for (int jj = 0; jj < 2; ++jj) {
                    int B = w + 4 * jj;
                    gll16(kbase + (size_t)((t + 1) * 128 + s * 64 + B * 8 + r8) * DH + cx * 8,
                          &Kbuf[1 - p][s * 4096 + B * 512]);
                    gll16(vbase + (size_t)(B * 8 + r8) * LSEQ + (t + 1) * 128 + s * 64 + cx * 8,
                          &Vbuf[1 - p][s * 4096 + B * 512]);
                }
        }

#pragma unroll
        for (int s = 0; s < 2; ++s) {
            const ushortT* Kb = &Kbuf[p][s * 4096];
            const ushortT* Vb = &Vbuf[p][s * 4096];
            bf16x8 kf[4][2], vf[4][2];
#pragma unroll
            for (int ct = 0; ct < 4; ++ct) {
                int R = 16 * ct + li;
                kf[ct][0] = *(const bf16x8*)&Kb[R * 64 + (quad ^ sw) * 8];
                kf[ct][1] = *(const bf16x8*)&Kb[R * 64 + ((quad + 4) ^ sw) * 8];
            }
#pragma unroll
            for (int dt = 0; dt < 4; ++dt) {
                int R = 16 * dt + li;
                vf[dt][0] = *(const bf16x8*)&Vb[R * 64 + (quad ^ sw) * 8];
                vf[dt][1] = *(const bf16x8*)&Vb[R * 64 + ((quad + 4) ^ sw) * 8];
            }
#pragma unroll
            for (int band = 0; band < 2; ++band) {
                // S^T = K Q^T (pre-scaled, log2 domain)
                f32x4 sa[4];
                __builtin_amdgcn_s_setprio(1);
#pragma unroll
                for (int ct = 0; ct < 4; ++ct) {
                    sa[ct] = MFMA16(kf[ct][0], qf[band][0], z4);
                    sa[ct] = MFMA16(kf[ct][1], qf[band][1], sa[ct]);
                }
                __builtin_amdgcn_s_setprio(0);
                // exp2, pack 4 keys (RTZ bf16) via v_perm, one b64 write
#pragma unroll
                for (int ct = 0; ct < 4; ++ct) {
                    unsigned u0 = __float_as_uint(__builtin_amdgcn_exp2f(sa[ct][0]));
                    unsigned u1 = __float_as_uint(__builtin_amdgcn_exp2f(sa[ct][1]));
                    unsigned u2 = __float_as_uint(__builtin_amdgcn_exp2f(sa[ct][2]));
                    unsigned u3 = __float_as_uint(__builtin_amdgcn_exp2f(sa[ct][3]));
                    uint2 pk;
                    pk.x = __builtin_amdgcn_perm(u1, u0, 0x07060302u);
                    pk.y = __builtin_amdgcn_perm(u3, u2, 0x07060302u);
                    *(uint2*)&PsT[pbase + (2 * ct + (quad >> 1)) * 128 + (quad & 1) * 4] = pk;
                }
                // read P^T fragments once; use for BOTH denominator and PV
                bf16x8 pt0 = *(const bf16x8*)&PsT[pbase + quad * 128];
                bf16x8 pt1 = *(const bf16x8*)&PsT[pbase + (4 + quad) * 128];
                __builtin_amdgcn_s_setprio(1);
                lsacc[band] = MFMA16(onesA, pt0, lsacc[band]);   // denom += col-sums
                lsacc[band] = MFMA16(onesA, pt1, lsacc[band]);
#pragma unroll
                for (int dt = 0; dt < 4; ++dt) {
                    oaccT[band][dt] = MFMA16(vf[dt][0], pt0, oaccT[band][dt]);
                    oaccT[band][dt] = MFMA16(vf[dt][1], pt1, oaccT[band][dt]);
                }
                __builtin_amdgcn_s_setprio(0);
            }
        }
        __syncthreads();   // DMA drained + all readers of buf[p] done
    }

    // ---- normalize + LDS-transpose store (coalesced 128B segments) ----
    ushortT* scr = (ushortT*)Kbuf + w * 2048;    // 4 KB per-wave, free after loop
#pragma unroll
    for (int band = 0; band < 2; ++band) {
        float inv = 1.0f / lsacc[band][0];
        const int ml = 16 * band + li;          // qrow-local (32 rows/wave)
#pragma unroll
        for (int dt = 0; dt < 4; ++dt) {
            const int dc = 4 * dt + quad;       // d-chunk
            ushort4 o4;
            o4.x = f2bf(oaccT[band][dt][0] * inv);
            o4.y = f2bf(oaccT[band][dt][1] * inv);
            o4.z = f2bf(oaccT[band][dt][2] * inv);
            o4.w = f2bf(oaccT[band][dt][3] * inv);
            *(ushort4*)&scr[ml * 64 + (dc ^ ((ml & 7) << 1)) * 4] = o4;
        }
    }
    {
        const int mlr = lane >> 4, cc = lane & 15;
#pragma unroll
        for (int it = 0; it < 8; ++it) {
            const int ml = it * 4 + mlr;
            ushort4 v4 = *(ushort4*)&scr[ml * 64 + (cc ^ ((ml & 7) << 1)) * 4];
            *(ushort4*)(obase + (size_t)(32 * w + ml) * DIMM + cc * 4) = v4;
        }
    }
}

// ---------------------------------------------------------------------------
extern "C" void kernel_launch(void* const* d_in, const int* in_sizes, int n_in,
                              void* d_out, int out_size, void* d_ws, size_t ws_size,
                              hipStream_t stream)
{
    const float* x    = (const float*)d_in[0];
    const float* Wqkv = (const float*)d_in[1];
    const float* bqkv = (const float*)d_in[2];
    const float* Wout = (const float*)d_in[3];
    const float* bout = (const float*)d_in[4];

    const size_t M4 = (size_t)4 * 1024 * 1024;
    ushortT* ws  = (ushortT*)d_ws;
    ushortT* xb  = ws;                                  // 4M shorts
    ushortT* qb  = ws + M4;                             // 4M
    ushortT* kb  = ws + 2 * M4;                         // 4M
    ushortT* vt  = ws + 3 * M4;                         // 4M  [B,H,d,L]
    ushortT* ob  = ws + 4 * M4;                         // 4M  [B,L,H*d]
    ushortT* wqt = ws + 5 * M4;                         // 3M
    ushortT* wot = ws + 5 * M4 + (size_t)3 * 1024 * 1024;  // 1M

    prep<<<8192, 256, 0, stream>>>(x, xb, Wqkv, Wout, wqt, wot);
    gemm_qkv<<<dim3(192), 512, 0, stream>>>(xb, wqt, bqkv, qb, kb, vt);
    attn<<<dim3(512), 256, 0, stream>>>(qb, kb, vt, ob);
    gemm_out<<<dim3(512), 256, 0, stream>>>(ob, wot, bout, (float*)d_out);
}